// Round 7
// baseline (266.762 us; speedup 1.0000x reference)
//
#include <hip/hip_runtime.h>
#include <math.h>

// NeuralMemory on MI355X — R14: epilogue-residual prefetch + rgemm 2-block/CU.
// R13 post-mortem: traffic cuts are no longer paying -> passes are
// latency-bound (~1/3 of fill BW). Fixes: (1) wgemm_k prefetches the 8
// residual uint2 loads (A or Rin) BEFORE the W-fill barrier — hipcc cannot
// hoist globals across __syncthreads, so these scattered 32B reads were
// eating raw HBM latency in the epilogue (T14 async-split, +16 VGPR);
// (2) rgemm back to split-K 64 (R9-verified grid (2,2,128) = 2 blocks/CU)
// restoring cross-block barrier overlap; pbuf 32 MB, gradstep reduces 64.

#define NTOK 32768
#define NM ((size_t)NTOK * 256)
#define LRc 1e-3f
#define WDc 1e-2f
#define EPSc 1e-8f

typedef __attribute__((ext_vector_type(8))) short bf16x8;
typedef __attribute__((ext_vector_type(4))) float f32x4;

__device__ __forceinline__ float b2f(unsigned short u) {
    union { unsigned int i; float f; } c;
    c.i = ((unsigned int)u) << 16;
    return c.f;
}
__device__ __forceinline__ unsigned short f2b(float f) {
    union { float f; unsigned int i; } c;
    c.f = f;
    unsigned int i = c.i;
    return (unsigned short)((i + 0x7FFFu + ((i >> 16) & 1u)) >> 16);
}
__device__ __forceinline__ float sigm(float z) { return 1.f / (1.f + __expf(-z)); }
__device__ __forceinline__ float siluf(float z) { return z * sigm(z); }
__device__ __forceinline__ float dsiluf(float z) {
    float s = sigm(z);
    return s * (1.f + z * (1.f - s));
}
__device__ __forceinline__ void unpack4(uint2 u, float* f) {
    f[0] = b2f(u.x & 0xFFFF); f[1] = b2f(u.x >> 16);
    f[2] = b2f(u.y & 0xFFFF); f[3] = b2f(u.y >> 16);
}
__device__ __forceinline__ uint2 pack4(const float* f) {
    uint2 o;
    o.x = (unsigned)f2b(f[0]) | ((unsigned)f2b(f[1]) << 16);
    o.y = (unsigned)f2b(f[2]) | ((unsigned)f2b(f[3]) << 16);
    return o;
}

#define WSTR 264   // W tile row stride in shorts (33x 16B units, odd => rotate)
#define SSTR 40    // scratch row stride in shorts (80 B, 16B-aligned)

// ---------------------------------------------------------------------------
// Projections: K,Q,V = X @ {Wk,Wq,Wv} in one kernel, z-loop inside block.
// Reads x fp32 directly (frag-shaped), converts in-register, computes alr
// from LDS-resident Wlr (n0==0 blocks write).
// ---------------------------------------------------------------------------
__global__ __launch_bounds__(512, 4) void wgemm3_k(
    const float* __restrict__ x, const float* __restrict__ Wlr,
    const float* __restrict__ blr, const unsigned short* __restrict__ wt,
    unsigned short* __restrict__ Kb, unsigned short* __restrict__ Qb,
    unsigned short* __restrict__ Vb, float* __restrict__ alr) {
    __shared__ unsigned short Ws[128 * WSTR];
    __shared__ unsigned short Sc[8][16 * SSTR];
    __shared__ float Ls[256];
    const int n0 = blockIdx.x * 128, m0 = blockIdx.y * 128;
    const int tid = threadIdx.x, lane = tid & 63, wv = tid >> 6;
    const int cc = lane & 15, q = lane >> 4;
    const int t0 = m0 + wv * 16, tok = t0 + cc;

    if (tid < 256) Ls[tid] = Wlr[tid];
    __syncthreads();  // Ls ready before the dot below

    // ---- X-frag load (fp32) + convert + alr partial dot
    const float* xp = x + (size_t)tok * 256 + q * 8;
    bf16x8 xf[8];
    float s = 0.f;
#pragma unroll
    for (int c = 0; c < 8; c++) {
        float xv[8];
        *(float4*)&xv[0] = *(const float4*)(xp + c * 32);
        *(float4*)&xv[4] = *(const float4*)(xp + c * 32 + 4);
        float wl[8];
        *(float4*)&wl[0] = *(const float4*)&Ls[c * 32 + q * 8];
        *(float4*)&wl[4] = *(const float4*)&Ls[c * 32 + q * 8 + 4];
        unsigned short us[8];
#pragma unroll
        for (int j = 0; j < 8; j++) {
            s += xv[j] * wl[j];
            us[j] = f2b(xv[j]);
        }
        xf[c] = *(bf16x8*)us;
    }
    s += __shfl_xor(s, 16);
    s += __shfl_xor(s, 32);
    if (n0 == 0 && q == 0) alr[tok] = 0.1f * sigm(s + blr[0]);

    unsigned short* sc = &Sc[wv][0];
    const int rtok = lane >> 2, roct = (lane & 3) * 8;
    unsigned short* const outs[3] = {Kb, Qb, Vb};

    for (int z = 0; z < 3; z++) {
        __syncthreads();  // prior z's Ws reads complete before refill
#pragma unroll
        for (int it = 0; it < 8; it++) {
            int i = it * 512 + tid;
            int row = i >> 5, g8 = i & 31;
            *(uint4*)&Ws[row * WSTR + g8 * 8] =
                *(const uint4*)(wt + (size_t)z * 65536 +
                                (size_t)(n0 + row) * 256 + g8 * 8);
        }
        __syncthreads();

        f32x4 acc[8];
#pragma unroll
        for (int t = 0; t < 8; t++) acc[t] = (f32x4){0.f, 0.f, 0.f, 0.f};
#pragma unroll
        for (int c = 0; c < 8; c++) {
#pragma unroll
            for (int nt = 0; nt < 8; nt++) {
                bf16x8 wf =
                    *(const bf16x8*)&Ws[(nt * 16 + cc) * WSTR + c * 32 + q * 8];
                acc[nt] = __builtin_amdgcn_mfma_f32_16x16x32_bf16(wf, xf[c],
                                                                  acc[nt], 0, 0, 0);
            }
        }

        unsigned short* Cb = outs[z];
#pragma unroll
        for (int pr = 0; pr < 4; pr++) {
#pragma unroll
            for (int h = 0; h < 2; h++) {
                const int nt = pr * 2 + h;
                f32x4 c4 = acc[nt];
                float o[4] = {c4[0], c4[1], c4[2], c4[3]};
                *(uint2*)&sc[cc * SSTR + h * 16 + q * 4] = pack4(o);
            }
            uint4 pk = *(const uint4*)&sc[rtok * SSTR + roct];
            *(uint4*)(Cb + (size_t)(t0 + rtok) * 256 + n0 + pr * 32 + roct) = pk;
        }
    }
}

// ---------------------------------------------------------------------------
// Operand-swapped tall GEMM: C[M,256] = X[M,256] @ B with Bt[n][k]=B[k][n].
// EPI 1: z=acc+bias; Zout=z; Cb = X+silu(z)           fwd layer 0
// EPI 5: z=acc+bias; h2=X+silu(z); dh=alr'* (h2-V);   fwd layer 1 + bwd elem
//        dz=dh*dsilu(z); Cb=dz; Rout=dh; colsum(dz)->gB
// EPI 2: dz0=(acc+Rin)*dsilu(Zin); Cb=dz0; colsum->gB bwd layer 0
// EPI 3: Cb = X + silu(acc+bias)                      retrieved L0
// EPI 4: Cf = X + silu(acc+bias)  (fp32 out)          retrieved L1
// R14: residual stream (A for 1/3/4/5, Rin for 2) prefetched BEFORE the
// W-fill barrier -> HBM latency hides under fill+MFMA instead of stalling
// the epilogue (compiler cannot hoist globals across __syncthreads).
// ---------------------------------------------------------------------------
template <int EPI>
__global__ __launch_bounds__(512, 4) void wgemm_k(
    const unsigned short* __restrict__ A, const unsigned short* __restrict__ Bt,
    const float* __restrict__ bias, const unsigned short* __restrict__ Rin,
    const unsigned short* __restrict__ Zin, const unsigned short* __restrict__ Vb,
    const float* __restrict__ alr, float* __restrict__ gB,
    unsigned short* __restrict__ Cb, float* __restrict__ Cf,
    unsigned short* __restrict__ Zout, unsigned short* __restrict__ Rout) {
    __shared__ unsigned short Ws[128 * WSTR];
    __shared__ unsigned short Sc[8][16 * SSTR];
    __shared__ float accsh[128];
    const int n0 = blockIdx.x * 128, m0 = blockIdx.y * 128;
    const int tid = threadIdx.x, lane = tid & 63, wv = tid >> 6;
    const int cc = lane & 15, q = lane >> 4;
    const int t0 = m0 + wv * 16, tok = t0 + cc;

    // ---- X-frag loads: 8 instrs off one base (imm offsets)
    const unsigned short* xp = A + (size_t)tok * 256 + q * 8;
    bf16x8 xf[8];
#pragma unroll
    for (int c = 0; c < 8; c++) xf[c] = *(const bf16x8*)(xp + c * 32);

    // ---- residual-stream prefetch (issued pre-barrier; consumed in epilogue)
    const unsigned short* Pf = (EPI == 2) ? Rin : A;
    uint2 pfA[8];
#pragma unroll
    for (int nt = 0; nt < 8; nt++)
        pfA[nt] = *(const uint2*)(Pf + (size_t)tok * 256 + n0 + nt * 16 + q * 4);
    float lalr = 0.f;
    if (EPI == 5) lalr = alr[tok] * (2.f / 256.f);

    if (EPI == 2 || EPI == 5) {
        if (tid < 128) accsh[tid] = 0.f;
    }

    // ---- W half-tile fill: [128 n-rows][256 k] shorts, padded stride
#pragma unroll
    for (int it = 0; it < 8; it++) {
        int i = it * 512 + tid;
        int row = i >> 5, g8 = i & 31;
        *(uint4*)&Ws[row * WSTR + g8 * 8] =
            *(const uint4*)(Bt + (size_t)(n0 + row) * 256 + g8 * 8);
    }
    __syncthreads();

    f32x4 acc[8];
#pragma unroll
    for (int t = 0; t < 8; t++) acc[t] = (f32x4){0.f, 0.f, 0.f, 0.f};

#pragma unroll
    for (int c = 0; c < 8; c++) {
#pragma unroll
        for (int nt = 0; nt < 8; nt++) {
            bf16x8 wf = *(const bf16x8*)&Ws[(nt * 16 + cc) * WSTR + c * 32 + q * 8];
            acc[nt] = __builtin_amdgcn_mfma_f32_16x16x32_bf16(wf, xf[c],
                                                              acc[nt], 0, 0, 0);
        }
    }

    // ---- epilogue: lane holds token tok, cols nt*16 + 4q + r (r=0..3)
    unsigned short* sc = &Sc[wv][0];
    const int rtok = lane >> 2, roct = (lane & 3) * 8;  // repack read indices

#pragma unroll
    for (int pr = 0; pr < 4; pr++) {  // tile pairs (2pr, 2pr+1) = 32 cols
        float o2[2][4], z2[2][4];     // primary / secondary quad outputs
#pragma unroll
        for (int h = 0; h < 2; h++) {
            const int nt = pr * 2 + h;
            const int gcol = n0 + nt * 16 + q * 4;
            const size_t off = (size_t)tok * 256 + gcol;
            f32x4 c = acc[nt];
            float v[4] = {c[0], c[1], c[2], c[3]};
            if (EPI == 1) {
                float bv[4], a[4];
                *(float4*)bv = *(const float4*)(bias + gcol);
                unpack4(pfA[nt], a);
#pragma unroll
                for (int r = 0; r < 4; r++) {
                    float z = v[r] + bv[r];
                    z2[h][r] = z;
                    o2[h][r] = a[r] + siluf(z);
                }
            } else if (EPI == 5) {
                float bv[4], a[4], vv[4];
                *(float4*)bv = *(const float4*)(bias + gcol);
                unpack4(pfA[nt], a);
                unpack4(*(const uint2*)(Vb + off), vv);
#pragma unroll
                for (int r = 0; r < 4; r++) {
                    float z = v[r] + bv[r];
                    float h2 = a[r] + siluf(z);
                    float dh = lalr * (h2 - vv[r]);
                    o2[h][r] = dh * dsiluf(z);  // dz
                    z2[h][r] = dh;              // dh
                }
            } else if (EPI == 2) {
                float ri[4], zi[4];
                unpack4(pfA[nt], ri);
                unpack4(*(const uint2*)(Zin + off), zi);
#pragma unroll
                for (int r = 0; r < 4; r++)
                    o2[h][r] = (v[r] + ri[r]) * dsiluf(zi[r]);
            } else {  // EPI 3 / 4
                float bv[4], a[4];
                *(float4*)bv = *(const float4*)(bias + gcol);
                unpack4(pfA[nt], a);
#pragma unroll
                for (int r = 0; r < 4; r++) o2[h][r] = a[r] + siluf(v[r] + bv[r]);
            }
            if (EPI == 4) {  // fp32 direct store: 4 lanes x 16 B = 64 B segs
                *(float4*)(Cf + off) = *(float4*)o2[h];
            }
            if (EPI == 2 || EPI == 5) {  // fused bias-grad column sums of dz
                float s0 = o2[h][0], s1 = o2[h][1], s2 = o2[h][2], s3 = o2[h][3];
#pragma unroll
                for (int m = 1; m < 16; m <<= 1) {
                    s0 += __shfl_xor(s0, m);
                    s1 += __shfl_xor(s1, m);
                    s2 += __shfl_xor(s2, m);
                    s3 += __shfl_xor(s3, m);
                }
                if (cc == 0) {
                    const int lc = nt * 16 + q * 4;
                    atomicAdd(&accsh[lc], s0);
                    atomicAdd(&accsh[lc + 1], s1);
                    atomicAdd(&accsh[lc + 2], s2);
                    atomicAdd(&accsh[lc + 3], s3);
                }
            }
        }
        if (EPI == 4) continue;
        // repack via wave-private scratch -> 64 B segment stores
#pragma unroll
        for (int h = 0; h < 2; h++)
            *(uint2*)&sc[cc * SSTR + h * 16 + q * 4] = pack4(o2[h]);
        uint4 pk = *(const uint4*)&sc[rtok * SSTR + roct];
        *(uint4*)(Cb + (size_t)(t0 + rtok) * 256 + n0 + pr * 32 + roct) = pk;
        if (EPI == 1 || EPI == 5) {  // second output (Zout / Rout)
#pragma unroll
            for (int h = 0; h < 2; h++)
                *(uint2*)&sc[cc * SSTR + h * 16 + q * 4] = pack4(z2[h]);
            uint4 pk2 = *(const uint4*)&sc[rtok * SSTR + roct];
            unsigned short* P2 = (EPI == 1) ? Zout : Rout;
            *(uint4*)(P2 + (size_t)(t0 + rtok) * 256 + n0 + pr * 32 + roct) = pk2;
        }
    }
    if (EPI == 2 || EPI == 5) {  // flush block-local col sums
        __syncthreads();
        if (tid < 128) atomicAdd(&gB[n0 + tid], accsh[tid]);
    }
}

// ---------------------------------------------------------------------------
// Reduction GEMM (weight grads): C[i][j] = sum_t A[t][i] B[t][j], split-K 64.
// Conflict-free swizzled transpose staging + prefetch (R9); grid (2,2,128)
// = 512 blocks = 2 blocks/CU for cross-block barrier overlap (R14 revert).
// ---------------------------------------------------------------------------
__global__ __launch_bounds__(512, 4) void rgemm_k(
    const unsigned short* __restrict__ Kb, const unsigned short* __restrict__ h1b,
    const unsigned short* __restrict__ dz0b,
    const unsigned short* __restrict__ dz1b, float* __restrict__ pbuf) {
    __shared__ unsigned short As[128 * 64];
    __shared__ unsigned short Bs2[128 * 64];
    const int z = blockIdx.z, layer = z >> 6, zc = z & 63;
    const unsigned short* Ag = layer ? h1b : Kb;
    const unsigned short* Bg = layer ? dz1b : dz0b;
    const int t0 = zc * 512;
    const int j0 = blockIdx.x * 128, i0 = blockIdx.y * 128;
    const int tid = threadIdx.x, lane = tid & 63, wave = tid >> 6;

    // staging role: threads 0-255 stage A, 256-511 stage B
    const int half = tid >> 8;
    const int t9 = tid & 255;
    const int ptq = t9 >> 4;          // token pair 0..15
    const int pi = (t9 & 15) * 8;     // col group base
    const unsigned short* sg = half ? Bg : Ag;
    const int nb = half ? j0 : i0;
    unsigned int* dst = (unsigned int*)(half ? Bs2 : As);
    const unsigned short* gp = sg + (size_t)(t0 + ptq * 2) * 256 + nb + pi;

    // wave output tile: 64 rows (i) x 32 cols (j)
    const int wr = (wave >> 2) * 64, wc = (wave & 3) * 32;
    const int fr = lane & 15, fkb = lane >> 4;

    f32x4 acc[4][2];
#pragma unroll
    for (int i = 0; i < 4; i++)
#pragma unroll
        for (int j = 0; j < 2; j++) acc[i][j] = (f32x4){0.f, 0.f, 0.f, 0.f};

    uint4 u0 = *(const uint4*)gp;
    uint4 u1 = *(const uint4*)(gp + 256);
    gp += 32 * 256;

    for (int it = 0; it < 16; it++) {
        // transpose-write: pack (token 2q, 2q+1) per col, swizzled slot
        const unsigned int* w0 = (const unsigned int*)&u0;
        const unsigned int* w1 = (const unsigned int*)&u1;
#pragma unroll
        for (int ii = 0; ii < 8; ii++) {
            unsigned int lo = (w0[ii >> 1] >> (16 * (ii & 1))) & 0xFFFFu;
            unsigned int hi = (w1[ii >> 1] >> (16 * (ii & 1))) & 0xFFFFu;
            const int col = pi + ii;
            const int s2 = ((col >> 3) ^ col) & 3;
            const int s4 = ((col >> 2) ^ (col >> 5)) & 1;
            dst[col * 32 + (ptq ^ (s2 << 2) ^ (s4 << 4))] = lo | (hi << 16);
        }
        __syncthreads();
        if (it < 15) {  // prefetch next K-chunk; latency hides under MFMA phase
            u0 = *(const uint4*)gp;
            u1 = *(const uint4*)(gp + 256);
            gp += 32 * 256;
        }
        bf16x8 af[4], bfr[2];
#pragma unroll
        for (int i = 0; i < 4; i++) {
            const int col = wr + i * 16 + fr;
            const int s2 = ((col >> 3) ^ col) & 3;
            const int s4 = ((col >> 2) ^ (col >> 5)) & 1;
            af[i] = *(const bf16x8*)&As[col * 64 + (fkb ^ s2 ^ (s4 << 2)) * 8];
        }
#pragma unroll
        for (int j = 0; j < 2; j++) {
            const int col = wc + j * 16 + fr;
            const int s2 = ((col >> 3) ^ col) & 3;
            const int s4 = ((col >> 2) ^ (col >> 5)) & 1;
            bfr[j] = *(const bf16x8*)&Bs2[col * 64 + (fkb ^ s2 ^ (s4 << 2)) * 8];
        }
#pragma unroll
        for (int i = 0; i < 4; i++)
#pragma unroll
            for (int j = 0; j < 2; j++)
                acc[i][j] = __builtin_amdgcn_mfma_f32_16x16x32_bf16(
                    af[i], bfr[j], acc[i][j], 0, 0, 0);
        __syncthreads();
    }

    float* P = pbuf + (size_t)((layer << 6) + zc) * 65536;
    const int r0 = fkb * 4;
#pragma unroll
    for (int mi = 0; mi < 4; mi++)
#pragma unroll
        for (int ni = 0; ni < 2; ni++) {
            f32x4 c = acc[mi][ni];
#pragma unroll
            for (int r = 0; r < 4; r++)
                P[(size_t)(i0 + wr + mi * 16 + r0 + r) * 256 +
                  (j0 + wc + ni * 16 + fr)] = c[r];
        }
}

// ---------------------------------------------------------------------------
// gradstep: reduce pbuf (64 chunks) -> g; surprises; AdamW for W and b.
// blocks 0..511: weights (256 threads each). block 512: biases.
// ---------------------------------------------------------------------------
__global__ __launch_bounds__(256) void gradstep_k(
    const float* __restrict__ pbuf, const float* __restrict__ Ws,
    const float* __restrict__ bs, const float* __restrict__ accB,
    unsigned short* __restrict__ nWt, float* __restrict__ nb,
    float* __restrict__ outSW, float* __restrict__ outSb) {
    const int bi = blockIdx.x;
    if (bi < 512) {
        const int idx = bi * 256 + threadIdx.x;  // 0..131071
        const int layer = idx >> 16, rc = idx & 65535;
        const float* p = pbuf + (size_t)layer * 64 * 65536 + rc;
        float g = 0.f;
#pragma unroll 8
        for (int c = 0; c < 64; c++) g += p[(size_t)c * 65536];
        outSW[idx] = -g;
        float nw = Ws[idx] * (1.f - LRc * WDc) - LRc * g / (fabsf(g) + EPSc);
        const int l = idx >> 16, k = (idx >> 8) & 255, n = idx & 255;
        nWt[(size_t)l * 65536 + n * 256 + k] = f2b(nw);
    } else {
        for (int i = threadIdx.x; i < 512; i += 256) {
            float g = accB[i];
            outSb[i] = -g;
            nb[i] = bs[i] * (1.f - LRc * WDc) - LRc * g / (fabsf(g) + EPSc);
        }
    }
}

// ---------------------------------------------------------------------------
// prep_w: blocks 0..1535 -> weight transpose+cvt (z=0..4) / cvt (z=5)
//         block 1536     -> zero accB[512]
// ---------------------------------------------------------------------------
__global__ __launch_bounds__(256) void prep_w_k(
    const float* __restrict__ Wk, const float* __restrict__ Wq,
    const float* __restrict__ Wv, const float* __restrict__ Ws,
    unsigned short* __restrict__ wt, float* __restrict__ accB) {
    const int bi = blockIdx.x;
    if (bi < 1536) {
        const int z = bi >> 8;
        const int idx = (bi & 255) * 256 + threadIdx.x;  // 0..65535
        const float* src = z == 0 ? Wk : z == 1 ? Wq : z == 2 ? Wv
                         : z == 3 ? Ws : Ws + 65536;
        unsigned short* dst = wt + (size_t)z * 65536;
        float v = src[idx];
        if (z == 5)
            dst[idx] = f2b(v);
        else
            dst[(idx & 255) * 256 + (idx >> 8)] = f2b(v);
    } else {
        accB[threadIdx.x] = 0.f;
        accB[threadIdx.x + 256] = 0.f;
    }
}

extern "C" void kernel_launch(void* const* d_in, const int* in_sizes, int n_in,
                              void* d_out, int out_size, void* d_ws,
                              size_t ws_size, hipStream_t stream) {
    const float* x = (const float*)d_in[0];
    const float* Wk = (const float*)d_in[1];
    const float* Wq = (const float*)d_in[2];
    const float* Wv = (const float*)d_in[3];
    const float* Wlr = (const float*)d_in[4];
    const float* blr = (const float*)d_in[5];
    const float* Ws = (const float*)d_in[6];
    const float* bs = (const float*)d_in[7];

    unsigned short* S = (unsigned short*)d_ws;
    unsigned short* xb = S + 0 * NM;  // r1b scratch (retrieval intermediate)
    unsigned short* Kb = S + 1 * NM;
    unsigned short* Qb = S + 2 * NM;
    unsigned short* Vb = S + 3 * NM;
    unsigned short* z0b = S + 4 * NM;
    unsigned short* h1b = S + 5 * NM;
    unsigned short* dz1b = S + 6 * NM;
    unsigned short* dh2b = S + 7 * NM;
    unsigned short* dz0b = S + 8 * NM;
    float* pbuf = (float*)(S + 9 * NM);  // 32 MB (slots 9-10): 2 x 64 chunks
    unsigned short* r1b = xb;

    unsigned short* wt = S + 11 * NM;
    unsigned short* W0t = wt + 3 * 65536;
    unsigned short* W1t = wt + 4 * 65536;
    unsigned short* W1b = wt + 5 * 65536;
    unsigned short* nW0t = wt + 6 * 65536;
    unsigned short* nW1t = wt + 7 * 65536;
    float* ft = (float*)(wt + 8 * 65536);
    float* alr = ft;              // 32768
    float* accB = ft + 32768;     // 512
    float* nb = accB + 512;       // 512

    float* out_ret = (float*)d_out;
    float* out_sW = out_ret + NM;
    float* out_sb = out_sW + 131072;

    dim3 blk5(512);
    dim3 blk(256);
    dim3 g_tall(2, 256);

    // prep: weight transpose/cvt + zero accB (x handled inside wgemm3_k)
    prep_w_k<<<1537, blk, 0, stream>>>(Wk, Wq, Wv, Ws, wt, accB);

    // projections K,Q,V (+ x->bf16 conversion + alr), z-loop inside block
    wgemm3_k<<<g_tall, blk5, 0, stream>>>(x, Wlr, blr, wt, Kb, Qb, Vb, alr);

    // fwd layer 0: h1 = K + silu(K@W0 + b0); saves z0
    wgemm_k<1><<<g_tall, blk5, 0, stream>>>(Kb, W0t, bs, nullptr, nullptr,
                                            nullptr, nullptr, nullptr, h1b,
                                            nullptr, z0b, nullptr);

    // fwd layer 1 + bwd elementwise: dz1, dh2 (+ colsum dz1 -> accB[256..])
    wgemm_k<5><<<g_tall, blk5, 0, stream>>>(h1b, W1t, bs + 256, nullptr,
                                            nullptr, Vb, alr, accB + 256,
                                            dz1b, nullptr, nullptr, dh2b);

    // bwd layer 0: dz0 = (dz1@W1^T + dh2) * dsilu(z0) (+ colsum -> accB[0..])
    wgemm_k<2><<<g_tall, blk5, 0, stream>>>(dz1b, W1b, nullptr, dh2b, z0b,
                                            nullptr, nullptr, accB, dz0b,
                                            nullptr, nullptr, nullptr);

    // weight grads: swizzled transpose-on-load split-K partials (2 blk/CU)
    rgemm_k<<<dim3(2, 2, 128), blk5, 0, stream>>>(Kb, h1b, dz0b, dz1b, pbuf);

    // reduce + surprises + AdamW (W and b) in one dispatch
    gradstep_k<<<513, blk, 0, stream>>>(pbuf, Ws, bs, accB, nW0t, nb, out_sW,
                                        out_sb);

    // retrieved with new weights (two tall passes)
    wgemm_k<3><<<g_tall, blk5, 0, stream>>>(Qb, nW0t, nb, nullptr, nullptr,
                                            nullptr, nullptr, nullptr, r1b,
                                            nullptr, nullptr, nullptr);
    wgemm_k<4><<<g_tall, blk5, 0, stream>>>(r1b, nW1t, nb + 256, nullptr,
                                            nullptr, nullptr, nullptr, nullptr,
                                            nullptr, out_ret, nullptr, nullptr);
}

// Round 9
// 252.342 us; speedup vs baseline: 1.0571x; 1.0571x over previous
//
#include <hip/hip_runtime.h>
#include <math.h>

// NeuralMemory on MI355X — R16: R15 resubmit with corrected read swizzle.
// R15's bench died on container acquisition (2nd infra-class failure; R5's
// identical error hit a verified-safe kernel). Audit found no fault source
// in the global_load_lds path, but DID find an 8-way LDS read conflict:
// pswz XORed unit bits 2-4 ((row&7)<<2) which only toggles 64B groups.
// Fix: full low-3-bit XOR at 16B-unit granularity — u_st = u ^ (row&7);
// reader unit = (c*4+q) ^ (cc&7). Each 16-lane cohort now covers all 8
// bank groups twice (2 lanes/bank = free, m136). Base remains R13
// (verified 247.7): W staging via __builtin_amdgcn_global_load_lds w=16,
// producers pre-swizzle wt-family buffers, activations stay linear.

#define NTOK 32768
#define NM ((size_t)NTOK * 256)
#define LRc 1e-3f
#define WDc 1e-2f
#define EPSc 1e-8f

typedef __attribute__((ext_vector_type(8))) short bf16x8;
typedef __attribute__((ext_vector_type(4))) float f32x4;

__device__ __forceinline__ float b2f(unsigned short u) {
    union { unsigned int i; float f; } c;
    c.i = ((unsigned int)u) << 16;
    return c.f;
}
__device__ __forceinline__ unsigned short f2b(float f) {
    union { float f; unsigned int i; } c;
    c.f = f;
    unsigned int i = c.i;
    return (unsigned short)((i + 0x7FFFu + ((i >> 16) & 1u)) >> 16);
}
__device__ __forceinline__ float sigm(float z) { return 1.f / (1.f + __expf(-z)); }
__device__ __forceinline__ float siluf(float z) { return z * sigm(z); }
__device__ __forceinline__ float dsiluf(float z) {
    float s = sigm(z);
    return s * (1.f + z * (1.f - s));
}
__device__ __forceinline__ void unpack4(uint2 u, float* f) {
    f[0] = b2f(u.x & 0xFFFF); f[1] = b2f(u.x >> 16);
    f[2] = b2f(u.y & 0xFFFF); f[3] = b2f(u.y >> 16);
}
__device__ __forceinline__ uint2 pack4(const float* f) {
    uint2 o;
    o.x = (unsigned)f2b(f[0]) | ((unsigned)f2b(f[1]) << 16);
    o.y = (unsigned)f2b(f[2]) | ((unsigned)f2b(f[3]) << 16);
    return o;
}

// direct global->LDS 16B staging (wave-uniform LDS base + lane*16B).
__device__ __forceinline__ void gload16(const unsigned short* g,
                                        unsigned short* l) {
#if __has_builtin(__builtin_amdgcn_global_load_lds)
    __builtin_amdgcn_global_load_lds(
        (const __attribute__((address_space(1))) unsigned int*)g,
        (__attribute__((address_space(3))) unsigned int*)l, 16, 0, 0);
#else
    *(uint4*)l = *(const uint4*)g;  // LDS is a linear image -> same layout
#endif
}

// producer-side 16B-unit pre-swizzle: unit u of row r stored at u ^ (r&7)
// (full low-3-bit XOR => reads spread over all 8 bank groups; involution)
__device__ __forceinline__ int pswz(int row, int col) {
    return (col & 7) | (((col >> 3) ^ (row & 7)) << 3);
}

#define SSTR 40    // scratch row stride in shorts (80 B, 16B-aligned)

// W half-tile fill: linear global_load_lds (global is pre-swizzled).
// Ws unpadded [128 rows][256 shorts]; L = it*512+tid indexes 16B units.
#define FILLW(SRC)                                                         \
    {                                                                      \
        _Pragma("unroll") for (int it_ = 0; it_ < 8; it_++) {              \
            const int L_ = it_ * 512 + tid;                                \
            gload16((SRC) + (size_t)L_ * 8,                                \
                    &Ws[(size_t)(it_ * 512 + wv * 64) * 8]);               \
        }                                                                  \
    }

// swizzled MFMA W-frag read: row = nt*16+cc, logical 16B-unit c*4+q
#define WREAD(nt_, c_)                                        \
    (*(const bf16x8*)&Ws[((nt_)*16 + cc) * 256 +              \
                         ((((c_)*4 + q) ^ (cc & 7)) << 3)])

// ---------------------------------------------------------------------------
// Projections: K,Q,V = X @ {Wk,Wq,Wv} in one kernel, z-loop inside block.
// Reads x fp32 directly (frag-shaped), converts in-register, computes alr
// from LDS-resident Wlr (n0==0 blocks write).
// ---------------------------------------------------------------------------
__global__ __launch_bounds__(512, 4) void wgemm3_k(
    const float* __restrict__ x, const float* __restrict__ Wlr,
    const float* __restrict__ blr, const unsigned short* __restrict__ wt,
    unsigned short* __restrict__ Kb, unsigned short* __restrict__ Qb,
    unsigned short* __restrict__ Vb, float* __restrict__ alr) {
    __shared__ __attribute__((aligned(16))) unsigned short Ws[128 * 256];
    __shared__ __attribute__((aligned(16))) unsigned short Sc[8][16 * SSTR];
    __shared__ float Ls[256];
    const int n0 = blockIdx.x * 128, m0 = blockIdx.y * 128;
    const int tid = threadIdx.x, lane = tid & 63, wv = tid >> 6;
    const int cc = lane & 15, q = lane >> 4;
    const int t0 = m0 + wv * 16, tok = t0 + cc;

    if (tid < 256) Ls[tid] = Wlr[tid];
    __syncthreads();  // Ls ready before the dot below

    // ---- X-frag load (fp32) + convert + alr partial dot
    const float* xp = x + (size_t)tok * 256 + q * 8;
    bf16x8 xf[8];
    float s = 0.f;
#pragma unroll
    for (int c = 0; c < 8; c++) {
        float xv[8];
        *(float4*)&xv[0] = *(const float4*)(xp + c * 32);
        *(float4*)&xv[4] = *(const float4*)(xp + c * 32 + 4);
        float wl[8];
        *(float4*)&wl[0] = *(const float4*)&Ls[c * 32 + q * 8];
        *(float4*)&wl[4] = *(const float4*)&Ls[c * 32 + q * 8 + 4];
        unsigned short us[8];
#pragma unroll
        for (int j = 0; j < 8; j++) {
            s += xv[j] * wl[j];
            us[j] = f2b(xv[j]);
        }
        xf[c] = *(bf16x8*)us;
    }
    s += __shfl_xor(s, 16);
    s += __shfl_xor(s, 32);
    if (n0 == 0 && q == 0) alr[tok] = 0.1f * sigm(s + blr[0]);

    unsigned short* sc = &Sc[wv][0];
    const int rtok = lane >> 2, roct = (lane & 3) * 8;
    unsigned short* const outs[3] = {Kb, Qb, Vb};

    for (int z = 0; z < 3; z++) {
        __syncthreads();  // prior z's Ws reads complete before refill
        FILLW(wt + (size_t)z * 65536 + (size_t)n0 * 256);
        __syncthreads();

        f32x4 acc[8];
#pragma unroll
        for (int t = 0; t < 8; t++) acc[t] = (f32x4){0.f, 0.f, 0.f, 0.f};
#pragma unroll
        for (int c = 0; c < 8; c++) {
#pragma unroll
            for (int nt = 0; nt < 8; nt++) {
                bf16x8 wf = WREAD(nt, c);
                acc[nt] = __builtin_amdgcn_mfma_f32_16x16x32_bf16(wf, xf[c],
                                                                  acc[nt], 0, 0, 0);
            }
        }

        unsigned short* Cb = outs[z];
#pragma unroll
        for (int pr = 0; pr < 4; pr++) {
#pragma unroll
            for (int h = 0; h < 2; h++) {
                const int nt = pr * 2 + h;
                f32x4 c4 = acc[nt];
                float o[4] = {c4[0], c4[1], c4[2], c4[3]};
                *(uint2*)&sc[cc * SSTR + h * 16 + q * 4] = pack4(o);
            }
            uint4 pk = *(const uint4*)&sc[rtok * SSTR + roct];
            *(uint4*)(Cb + (size_t)(t0 + rtok) * 256 + n0 + pr * 32 + roct) = pk;
        }
    }
}

// ---------------------------------------------------------------------------
// Operand-swapped tall GEMM: C[M,256] = X[M,256] @ B with Bt[n][k]=B[k][n].
// EPI 1: z=acc+bias; Zout=z; Cb = X+silu(z)           fwd layer 0
// EPI 5: z=acc+bias; h2=X+silu(z); dh=alr'* (h2-V);   fwd layer 1 + bwd elem
//        dz=dh*dsilu(z); Cb=dz; Rout=dh; colsum(dz)->gB
// EPI 2: dz0=(acc+Rin)*dsilu(Zin); Cb=dz0; colsum->gB bwd layer 0
// EPI 3: Cb = X + silu(acc+bias)                      retrieved L0
// EPI 4: Cf = X + silu(acc+bias)  (fp32 out)          retrieved L1
// ---------------------------------------------------------------------------
template <int EPI>
__global__ __launch_bounds__(512, 4) void wgemm_k(
    const unsigned short* __restrict__ A, const unsigned short* __restrict__ Bt,
    const float* __restrict__ bias, const unsigned short* __restrict__ Rin,
    const unsigned short* __restrict__ Zin, const unsigned short* __restrict__ Vb,
    const float* __restrict__ alr, float* __restrict__ gB,
    unsigned short* __restrict__ Cb, float* __restrict__ Cf,
    unsigned short* __restrict__ Zout, unsigned short* __restrict__ Rout) {
    __shared__ __attribute__((aligned(16))) unsigned short Ws[128 * 256];
    __shared__ __attribute__((aligned(16))) unsigned short Sc[8][16 * SSTR];
    __shared__ float accsh[128];
    const int n0 = blockIdx.x * 128, m0 = blockIdx.y * 128;
    const int tid = threadIdx.x, lane = tid & 63, wv = tid >> 6;
    const int cc = lane & 15, q = lane >> 4;

    // ---- X-frag loads: 8 instrs off one base (imm offsets)
    const int t0 = m0 + wv * 16;
    const unsigned short* xp = A + (size_t)(t0 + cc) * 256 + q * 8;
    bf16x8 xf[8];
#pragma unroll
    for (int c = 0; c < 8; c++) xf[c] = *(const bf16x8*)(xp + c * 32);

    if (EPI == 2 || EPI == 5) {
        if (tid < 128) accsh[tid] = 0.f;
    }

    // ---- W half-tile fill: direct global->LDS (pre-swizzled source)
    FILLW(Bt + (size_t)n0 * 256);
    __syncthreads();

    f32x4 acc[8];
#pragma unroll
    for (int t = 0; t < 8; t++) acc[t] = (f32x4){0.f, 0.f, 0.f, 0.f};

#pragma unroll
    for (int c = 0; c < 8; c++) {
#pragma unroll
        for (int nt = 0; nt < 8; nt++) {
            bf16x8 wf = WREAD(nt, c);
            acc[nt] = __builtin_amdgcn_mfma_f32_16x16x32_bf16(wf, xf[c],
                                                              acc[nt], 0, 0, 0);
        }
    }

    // ---- epilogue: lane holds token t0+cc, cols nt*16 + 4q + r (r=0..3)
    const int tok = t0 + cc;
    float lalr = 0.f;
    if (EPI == 5) lalr = alr[tok] * (2.f / 256.f);
    unsigned short* sc = &Sc[wv][0];
    const int rtok = lane >> 2, roct = (lane & 3) * 8;  // repack read indices

#pragma unroll
    for (int pr = 0; pr < 4; pr++) {  // tile pairs (2pr, 2pr+1) = 32 cols
        float o2[2][4], z2[2][4];     // primary / secondary quad outputs
#pragma unroll
        for (int h = 0; h < 2; h++) {
            const int nt = pr * 2 + h;
            const int gcol = n0 + nt * 16 + q * 4;
            const size_t off = (size_t)tok * 256 + gcol;
            f32x4 c = acc[nt];
            float v[4] = {c[0], c[1], c[2], c[3]};
            if (EPI == 1) {
                float bv[4], a[4];
                *(float4*)bv = *(const float4*)(bias + gcol);
                unpack4(*(const uint2*)(A + off), a);
#pragma unroll
                for (int r = 0; r < 4; r++) {
                    float z = v[r] + bv[r];
                    z2[h][r] = z;
                    o2[h][r] = a[r] + siluf(z);
                }
            } else if (EPI == 5) {
                float bv[4], a[4], vv[4];
                *(float4*)bv = *(const float4*)(bias + gcol);
                unpack4(*(const uint2*)(A + off), a);
                unpack4(*(const uint2*)(Vb + off), vv);
#pragma unroll
                for (int r = 0; r < 4; r++) {
                    float z = v[r] + bv[r];
                    float h2 = a[r] + siluf(z);
                    float dh = lalr * (h2 - vv[r]);
                    o2[h][r] = dh * dsiluf(z);  // dz
                    z2[h][r] = dh;              // dh
                }
            } else if (EPI == 2) {
                float ri[4], zi[4];
                unpack4(*(const uint2*)(Rin + off), ri);
                unpack4(*(const uint2*)(Zin + off), zi);
#pragma unroll
                for (int r = 0; r < 4; r++)
                    o2[h][r] = (v[r] + ri[r]) * dsiluf(zi[r]);
            } else {  // EPI 3 / 4
                float bv[4], a[4];
                *(float4*)bv = *(const float4*)(bias + gcol);
                unpack4(*(const uint2*)(A + off), a);
#pragma unroll
                for (int r = 0; r < 4; r++) o2[h][r] = a[r] + siluf(v[r] + bv[r]);
            }
            if (EPI == 4) {  // fp32 direct store: 4 lanes x 16 B = 64 B segs
                *(float4*)(Cf + off) = *(float4*)o2[h];
            }
            if (EPI == 2 || EPI == 5) {  // fused bias-grad column sums of dz
                float s0 = o2[h][0], s1 = o2[h][1], s2 = o2[h][2], s3 = o2[h][3];
#pragma unroll
                for (int m = 1; m < 16; m <<= 1) {
                    s0 += __shfl_xor(s0, m);
                    s1 += __shfl_xor(s1, m);
                    s2 += __shfl_xor(s2, m);
                    s3 += __shfl_xor(s3, m);
                }
                if (cc == 0) {
                    const int lc = nt * 16 + q * 4;
                    atomicAdd(&accsh[lc], s0);
                    atomicAdd(&accsh[lc + 1], s1);
                    atomicAdd(&accsh[lc + 2], s2);
                    atomicAdd(&accsh[lc + 3], s3);
                }
            }
        }
        if (EPI == 4) continue;
        // repack via wave-private scratch -> 64 B segment stores
#pragma unroll
        for (int h = 0; h < 2; h++)
            *(uint2*)&sc[cc * SSTR + h * 16 + q * 4] = pack4(o2[h]);
        uint4 pk = *(const uint4*)&sc[rtok * SSTR + roct];
        *(uint4*)(Cb + (size_t)(t0 + rtok) * 256 + n0 + pr * 32 + roct) = pk;
        if (EPI == 1 || EPI == 5) {  // second output (Zout / Rout)
#pragma unroll
            for (int h = 0; h < 2; h++)
                *(uint2*)&sc[cc * SSTR + h * 16 + q * 4] = pack4(z2[h]);
            uint4 pk2 = *(const uint4*)&sc[rtok * SSTR + roct];
            unsigned short* P2 = (EPI == 1) ? Zout : Rout;
            *(uint4*)(P2 + (size_t)(t0 + rtok) * 256 + n0 + pr * 32 + roct) = pk2;
        }
    }
    if (EPI == 2 || EPI == 5) {  // flush block-local col sums
        __syncthreads();
        if (tid < 128) atomicAdd(&gB[n0 + tid], accsh[tid]);
    }
}

// ---------------------------------------------------------------------------
// Reduction GEMM (weight grads): C[i][j] = sum_t A[t][i] B[t][j], split-K 32.
// Conflict-free swizzled transpose staging + prefetch + 8 waves/block (R9).
// ---------------------------------------------------------------------------
__global__ __launch_bounds__(512, 4) void rgemm_k(
    const unsigned short* __restrict__ Kb, const unsigned short* __restrict__ h1b,
    const unsigned short* __restrict__ dz0b,
    const unsigned short* __restrict__ dz1b, float* __restrict__ pbuf) {
    __shared__ unsigned short As[128 * 64];
    __shared__ unsigned short Bs2[128 * 64];
    const int z = blockIdx.z, layer = z >> 5, zc = z & 31;
    const unsigned short* Ag = layer ? h1b : Kb;
    const unsigned short* Bg = layer ? dz1b : dz0b;
    const int t0 = zc * 1024;
    const int j0 = blockIdx.x * 128, i0 = blockIdx.y * 128;
    const int tid = threadIdx.x, lane = tid & 63, wave = tid >> 6;

    // staging role: threads 0-255 stage A, 256-511 stage B
    const int half = tid >> 8;
    const int t9 = tid & 255;
    const int ptq = t9 >> 4;          // token pair 0..15
    const int pi = (t9 & 15) * 8;     // col group base
    const unsigned short* sg = half ? Bg : Ag;
    const int nb = half ? j0 : i0;
    unsigned int* dst = (unsigned int*)(half ? Bs2 : As);
    const unsigned short* gp = sg + (size_t)(t0 + ptq * 2) * 256 + nb + pi;

    // wave output tile: 64 rows (i) x 32 cols (j)
    const int wr = (wave >> 2) * 64, wc = (wave & 3) * 32;
    const int fr = lane & 15, fkb = lane >> 4;

    f32x4 acc[4][2];
#pragma unroll
    for (int i = 0; i < 4; i++)
#pragma unroll
        for (int j = 0; j < 2; j++) acc[i][j] = (f32x4){0.f, 0.f, 0.f, 0.f};

    uint4 u0 = *(const uint4*)gp;
    uint4 u1 = *(const uint4*)(gp + 256);
    gp += 32 * 256;

    for (int it = 0; it < 32; it++) {
        // transpose-write: pack (token 2q, 2q+1) per col, swizzled slot
        const unsigned int* w0 = (const unsigned int*)&u0;
        const unsigned int* w1 = (const unsigned int*)&u1;
#pragma unroll
        for (int ii = 0; ii < 8; ii++) {
            unsigned int lo = (w0[ii >> 1] >> (16 * (ii & 1))) & 0xFFFFu;
            unsigned int hi = (w1[ii >> 1] >> (16 * (ii & 1))) & 0xFFFFu;
            const int col = pi + ii;
            const int s2 = ((col >> 3) ^ col) & 3;
            const int s4 = ((col >> 2) ^ (col >> 5)) & 1;
            dst[col * 32 + (ptq ^ (s2 << 2) ^ (s4 << 4))] = lo | (hi << 16);
        }
        __syncthreads();
        if (it < 31) {  // prefetch next K-chunk; latency hides under MFMA phase
            u0 = *(const uint4*)gp;
            u1 = *(const uint4*)(gp + 256);
            gp += 32 * 256;
        }
        bf16x8 af[4], bfr[2];
#pragma unroll
        for (int i = 0; i < 4; i++) {
            const int col = wr + i * 16 + fr;
            const int s2 = ((col >> 3) ^ col) & 3;
            const int s4 = ((col >> 2) ^ (col >> 5)) & 1;
            af[i] = *(const bf16x8*)&As[col * 64 + (fkb ^ s2 ^ (s4 << 2)) * 8];
        }
#pragma unroll
        for (int j = 0; j < 2; j++) {
            const int col = wc + j * 16 + fr;
            const int s2 = ((col >> 3) ^ col) & 3;
            const int s4 = ((col >> 2) ^ (col >> 5)) & 1;
            bfr[j] = *(const bf16x8*)&Bs2[col * 64 + (fkb ^ s2 ^ (s4 << 2)) * 8];
        }
#pragma unroll
        for (int i = 0; i < 4; i++)
#pragma unroll
            for (int j = 0; j < 2; j++)
                acc[i][j] = __builtin_amdgcn_mfma_f32_16x16x32_bf16(
                    af[i], bfr[j], acc[i][j], 0, 0, 0);
        __syncthreads();
    }

    float* P = pbuf + (size_t)((layer << 5) + zc) * 65536;
    const int r0 = fkb * 4;
#pragma unroll
    for (int mi = 0; mi < 4; mi++)
#pragma unroll
        for (int ni = 0; ni < 2; ni++) {
            f32x4 c = acc[mi][ni];
#pragma unroll
            for (int r = 0; r < 4; r++)
                P[(size_t)(i0 + wr + mi * 16 + r0 + r) * 256 +
                  (j0 + wc + ni * 16 + fr)] = c[r];
        }
}

// ---------------------------------------------------------------------------
// gradstep: reduce pbuf (32 chunks) -> g; surprises; AdamW for W and b.
// blocks 0..511: weights (256 threads each). block 512: biases.
// nWt written with the producer-side pre-swizzle (consumed by FILLW).
// ---------------------------------------------------------------------------
__global__ __launch_bounds__(256) void gradstep_k(
    const float* __restrict__ pbuf, const float* __restrict__ Ws,
    const float* __restrict__ bs, const float* __restrict__ accB,
    unsigned short* __restrict__ nWt, float* __restrict__ nb,
    float* __restrict__ outSW, float* __restrict__ outSb) {
    const int bi = blockIdx.x;
    if (bi < 512) {
        const int idx = bi * 256 + threadIdx.x;  // 0..131071
        const int layer = idx >> 16, rc = idx & 65535;
        const float* p = pbuf + (size_t)layer * 32 * 65536 + rc;
        float g = 0.f;
#pragma unroll 8
        for (int c = 0; c < 32; c++) g += p[(size_t)c * 65536];
        outSW[idx] = -g;
        float nw = Ws[idx] * (1.f - LRc * WDc) - LRc * g / (fabsf(g) + EPSc);
        const int l = idx >> 16, k = (idx >> 8) & 255, n = idx & 255;
        nWt[(size_t)l * 65536 + n * 256 + pswz(n, k)] = f2b(nw);
    } else {
        for (int i = threadIdx.x; i < 512; i += 256) {
            float g = accB[i];
            outSb[i] = -g;
            nb[i] = bs[i] * (1.f - LRc * WDc) - LRc * g / (fabsf(g) + EPSc);
        }
    }
}

// ---------------------------------------------------------------------------
// prep_w: blocks 0..1535 -> weight transpose+cvt (z=0..4) / cvt (z=5),
//         all with the producer-side 16B-unit pre-swizzle.
//         block 1536     -> zero accB[512]
// ---------------------------------------------------------------------------
__global__ __launch_bounds__(256) void prep_w_k(
    const float* __restrict__ Wk, const float* __restrict__ Wq,
    const float* __restrict__ Wv, const float* __restrict__ Ws,
    unsigned short* __restrict__ wt, float* __restrict__ accB) {
    const int bi = blockIdx.x;
    if (bi < 1536) {
        const int z = bi >> 8;
        const int idx = (bi & 255) * 256 + threadIdx.x;  // 0..65535
        const float* src = z == 0 ? Wk : z == 1 ? Wq : z == 2 ? Wv
                         : z == 3 ? Ws : Ws + 65536;
        unsigned short* dst = wt + (size_t)z * 65536;
        float v = src[idx];
        int row, col;
        if (z == 5) { row = idx >> 8; col = idx & 255; }
        else        { row = idx & 255; col = idx >> 8; }
        dst[row * 256 + pswz(row, col)] = f2b(v);
    } else {
        accB[threadIdx.x] = 0.f;
        accB[threadIdx.x + 256] = 0.f;
    }
}

extern "C" void kernel_launch(void* const* d_in, const int* in_sizes, int n_in,
                              void* d_out, int out_size, void* d_ws,
                              size_t ws_size, hipStream_t stream) {
    const float* x = (const float*)d_in[0];
    const float* Wk = (const float*)d_in[1];
    const float* Wq = (const float*)d_in[2];
    const float* Wv = (const float*)d_in[3];
    const float* Wlr = (const float*)d_in[4];
    const float* blr = (const float*)d_in[5];
    const float* Ws = (const float*)d_in[6];
    const float* bs = (const float*)d_in[7];

    unsigned short* S = (unsigned short*)d_ws;
    unsigned short* xb = S + 0 * NM;  // r1b scratch (retrieval intermediate)
    unsigned short* Kb = S + 1 * NM;
    unsigned short* Qb = S + 2 * NM;
    unsigned short* Vb = S + 3 * NM;
    unsigned short* z0b = S + 4 * NM;
    unsigned short* h1b = S + 5 * NM;
    unsigned short* dz1b = S + 6 * NM;
    unsigned short* dh2b = S + 7 * NM;
    unsigned short* dz0b = S + 8 * NM;
    float* pbuf = (float*)(S + 9 * NM);  // 16 MB (slot 9): 2 layers x 32 chunks
    unsigned short* r1b = xb;

    unsigned short* wt = S + 11 * NM;
    unsigned short* W0t = wt + 3 * 65536;
    unsigned short* W1t = wt + 4 * 65536;
    unsigned short* W1b = wt + 5 * 65536;
    unsigned short* nW0t = wt + 6 * 65536;
    unsigned short* nW1t = wt + 7 * 65536;
    float* ft = (float*)(wt + 8 * 65536);
    float* alr = ft;              // 32768
    float* accB = ft + 32768;     // 512
    float* nb = accB + 512;       // 512

    float* out_ret = (float*)d_out;
    float* out_sW = out_ret + NM;
    float* out_sb = out_sW + 131072;

    dim3 blk5(512);
    dim3 blk(256);
    dim3 g_tall(2, 256);

    // prep: weight transpose/cvt (pre-swizzled) + zero accB
    prep_w_k<<<1537, blk, 0, stream>>>(Wk, Wq, Wv, Ws, wt, accB);

    // projections K,Q,V (+ x->bf16 conversion + alr), z-loop inside block
    wgemm3_k<<<g_tall, blk5, 0, stream>>>(x, Wlr, blr, wt, Kb, Qb, Vb, alr);

    // fwd layer 0: h1 = K + silu(K@W0 + b0); saves z0
    wgemm_k<1><<<g_tall, blk5, 0, stream>>>(Kb, W0t, bs, nullptr, nullptr,
                                            nullptr, nullptr, nullptr, h1b,
                                            nullptr, z0b, nullptr);

    // fwd layer 1 + bwd elementwise: dz1, dh2 (+ colsum dz1 -> accB[256..])
    wgemm_k<5><<<g_tall, blk5, 0, stream>>>(h1b, W1t, bs + 256, nullptr,
                                            nullptr, Vb, alr, accB + 256,
                                            dz1b, nullptr, nullptr, dh2b);

    // bwd layer 0: dz0 = (dz1@W1^T + dh2) * dsilu(z0) (+ colsum -> accB[0..])
    wgemm_k<2><<<g_tall, blk5, 0, stream>>>(dz1b, W1b, nullptr, dh2b, z0b,
                                            nullptr, nullptr, accB, dz0b,
                                            nullptr, nullptr, nullptr);

    // weight grads: swizzled transpose-on-load split-K partials
    rgemm_k<<<dim3(2, 2, 64), blk5, 0, stream>>>(Kb, h1b, dz0b, dz1b, pbuf);

    // reduce + surprises + AdamW (W and b) in one dispatch
    gradstep_k<<<513, blk, 0, stream>>>(pbuf, Ws, bs, accB, nW0t, nb, out_sW,
                                        out_sb);

    // retrieved with new weights (two tall passes)
    wgemm_k<3><<<g_tall, blk5, 0, stream>>>(Qb, nW0t, nb, nullptr, nullptr,
                                            nullptr, nullptr, nullptr, r1b,
                                            nullptr, nullptr, nullptr);
    wgemm_k<4><<<g_tall, blk5, 0, stream>>>(r1b, nW1t, nb + 256, nullptr,
                                            nullptr, nullptr, nullptr, nullptr,
                                            nullptr, out_ret, nullptr, nullptr);
}